// Round 17
// baseline (108.320 us; speedup 1.0000x reference)
//
#include <hip/hip_runtime.h>
#include <math.h>

// Problem: X[16384,64] fp32, W[8192,64] fp32 -> argmin_c ||x-w_c||^2 (int32)
#define EMB     64
#define NTOK    8192
#define NQ      16384
#define TPB     256               // 4 waves: 2 q-halves x 2 c-halves
#define CSPLIT  4
#define CRANGE  (NTOK / CSPLIT)   // 2048 codewords per y-split
#define BQ      128               // query rows per block
#define TILE_C  128               // codewords staged in LDS per iteration
#define NT      (CRANGE / TILE_C) // 16 tiles
#define TCH     (TILE_C * EMB)    // halves per tile buffer (8192 = 16KB)
#define NXBLK   (NQ / BQ)         // 128

typedef _Float16 half8 __attribute__((ext_vector_type(8)));
typedef float    f32x4 __attribute__((ext_vector_type(4)));

// async global->LDS DMA, 16B per lane (dest = wave-uniform base + lane*16)
__device__ __forceinline__ void gl2lds16(const _Float16* g, _Float16* l) {
    __builtin_amdgcn_global_load_lds(
        (const __attribute__((address_space(1))) unsigned int*)g,
        (__attribute__((address_space(3))) unsigned int*)l, 16, 0, 0);
}

// monotone float->uint map: m(a) < m(b) iff a < b (no NaNs here)
__device__ __forceinline__ unsigned long long pack_di(float d, int idx) {
    unsigned int u = __float_as_uint(d);
    unsigned int m = (u & 0x80000000u) ? ~u : (u | 0x80000000u);
    return ((unsigned long long)m << 32) | (unsigned int)idx;
}

// ---------------------------------------------------------------------------
// Prep v3 (verified r11-r16) -- COALESCED. One thread per input 8-float
// segment (65536 threads): reads row c = gtid>>3, seg = gtid&7 (wave covers
// contiguous 2KB). Writes Wh/Wl in 16x16 MFMA-FRAGMENT ORDER:
//   chunk u = g*128 + kb*64 + lq*16 + r holds W[g*16+r][kb*32+lq*8..+7].
// ynorm via 3-step shfl_xor tree over the 8 same-row lanes.
// Also inits packed[]/cnt[].
// ---------------------------------------------------------------------------
__global__ void prep_kernel(const float* __restrict__ W,
                            _Float16* __restrict__ Wh, _Float16* __restrict__ Wl,
                            float* __restrict__ ynorm,
                            unsigned long long* __restrict__ packed,
                            int* __restrict__ cnt) {
    const int gtid = blockIdx.x * blockDim.x + threadIdx.x;   // 0..65535
    if (gtid < NQ)    packed[gtid] = ~0ull;
    if (gtid < NXBLK) cnt[gtid] = 0;

    const int c   = gtid >> 3;          // input row (0..8191)
    const int seg = gtid & 7;           // 8-float segment within row
    const float* wp = W + (size_t)c * EMB + seg * 8;
    float4 v0 = *(const float4*)wp;     // coalesced: wave covers 2KB contiguous
    float4 v1 = *(const float4*)(wp + 4);
    float xv[8] = {v0.x, v0.y, v0.z, v0.w, v1.x, v1.y, v1.z, v1.w};
    half8 h, l;
    float s8 = 0.f;
#pragma unroll
    for (int j = 0; j < 8; ++j) {
        _Float16 hh = (_Float16)xv[j];
        h[j] = hh;
        l[j] = (_Float16)(xv[j] - (float)hh);
        s8 = fmaf(xv[j], xv[j], s8);
    }
    const int g = c >> 4, r = c & 15, kb = seg >> 2, lq = seg & 3;
    const size_t u = (size_t)g * 128 + kb * 64 + lq * 16 + r;
    *(half8*)(Wh + u * 8) = h;
    *(half8*)(Wl + u * 8) = l;

    // ynorm: tree-sum the 8 segment partials of row c (lanes 8-aligned)
    s8 += __shfl_xor(s8, 1, 64);
    s8 += __shfl_xor(s8, 2, 64);
    s8 += __shfl_xor(s8, 4, 64);
    if (seg == 0) ynorm[c] = s8;
}

// ---------------------------------------------------------------------------
// Main: r12/r16 numerics (3-term fp16 split, -2 prescale, yn-fold -- all
// verified absmax=0) with the T3+T4 COMBINED schedule: 4 phases/tile, each
// {vmcnt(6) counted wait; s_barrier; ds_read phase frags; issue 2 stage
// DMAs for NEXT tile's SAME phase; lgkmcnt(0); 24 MFMA; epilogue}.
// NO vmcnt(0) in the loop -- 8 DMAs stay in flight across every barrier.
// Why this is new: m218 says "T3's gain IS T4" -- 8-phase-with-drain0 ~=
// 1-phase. r15 tested phases WITH drain0 (predicted null, measured null);
// r7 tested counted-wait WITHOUT phases (null). This is the combination.
// Stage slicing: wave(wq,wy) phase ct stages chunks wy*512+ct*128+wq*64;
// phase-ct read set [wy*512+ct*128,+128) = union of the two wq slices.
// vmcnt accounting (hand-verified): steady state 8 outstanding at phase
// entry; oldest 2 = stage of THIS phase's region (issued 4 phases ago);
// wait-before-barrier makes the partner wave's landing visible too.
// Last tile: decreasing ladder vmcnt(6/4/2/0) (no new issues replenish).
// Session ledger (measured -- do not regress):
//  - launch_bounds arg2: (256,3)->cap 170 ok; >=4 waves/SIMD -> 64 = spill.
//  - coop grid.sync 3x slower (r4); __threadfence finisher +34us (r5).
//  - occupancy worse 3x (r3/r10/r13); 32x32 shape worse (r14).
//  - r16 baseline: main 57.5us = 896 TF effective = the documented ~900 TF
//    m97-structure ceiling. total-vs-main ~47us = fixed harness OH.
// ---------------------------------------------------------------------------
__global__ __launch_bounds__(TPB, 3) void vq_mfma_kernel(
    const float* __restrict__ X,
    const _Float16* __restrict__ Wh, const _Float16* __restrict__ Wl,
    const float* __restrict__ ynorm,
    unsigned long long* __restrict__ packed,
    int* __restrict__ cnt, int* __restrict__ out)
{
    __shared__ __align__(16) _Float16 LdsH0[TCH];
    __shared__ __align__(16) _Float16 LdsH1[TCH];
    __shared__ __align__(16) _Float16 LdsL0[TCH];
    __shared__ __align__(16) _Float16 LdsL1[TCH];
    __shared__ __align__(16) float    Lyn[CRANGE];
    __shared__ float RedV[2][BQ];
    __shared__ int   RedI[2][BQ];
    __shared__ int   fin;

    const int t    = threadIdx.x;
    const int lane = t & 63;
    const int wid  = t >> 6;       // 0..3
    const int wq   = wid & 1;      // q half (0/1)
    const int wy   = wid >> 1;     // c half (0/1)
    const int l15  = lane & 15;
    const int lq   = lane >> 4;    // 0..3

    const int bx     = blockIdx.x;
    const int qblk   = bx * BQ;
    const int qbase  = qblk + wq * 64;
    const int cbase0 = blockIdx.y * CRANGE;

    // --- prologue: stage ALL of tile 0 into buf0 (per-phase slicing) ---
    {
        const size_t gsbase = (size_t)(cbase0 >> 4) * 1024;   // halves
#pragma unroll
        for (int ct = 0; ct < 4; ++ct) {
            const int jw = wy * 512 + ct * 128 + wq * 64;     // wave-uniform
            gl2lds16(Wh + gsbase + (size_t)(jw + lane) * 8, LdsH0 + (size_t)jw * 8);
            gl2lds16(Wl + gsbase + (size_t)(jw + lane) * 8, LdsL0 + (size_t)jw * 8);
        }
    }

    // --- stage the block's full ynorm range once ---
    for (int u = t; u < CRANGE / 4; u += TPB)
        ((float4*)Lyn)[u] = ((const float4*)(ynorm + cbase0))[u];

    // --- A fragments PRE-SCALED by -2 (exact): X rows (qbase + mt*16 + l15),
    //     k = kb*32 + lq*8 + j. Products become -2*x*w; acc init = yn. ---
    half8 ah[4][2], al[4][2];
#pragma unroll
    for (int mt = 0; mt < 4; ++mt) {
#pragma unroll
        for (int kb = 0; kb < 2; ++kb) {
            const float* xp = X + (size_t)(qbase + mt * 16 + l15) * EMB + kb * 32 + lq * 8;
            float4 v0 = *(const float4*)xp;
            float4 v1 = *(const float4*)(xp + 4);
            float xv[8] = {v0.x, v0.y, v0.z, v0.w, v1.x, v1.y, v1.z, v1.w};
            half8 h, l;
#pragma unroll
            for (int j = 0; j < 8; ++j) {
                _Float16 hh = (_Float16)xv[j];               // hi split (unscaled)
                float    rr = xv[j] - (float)hh;             // exact residual
                h[j] = (_Float16)(-2.0f * (float)hh);        // exact x2 scale
                l[j] = (_Float16)(-2.0f * rr);               // exact x2 scale
            }
            ah[mt][kb] = h;
            al[mt][kb] = l;
        }
    }

    float minv[4][4];
    int   mini[4][4];
#pragma unroll
    for (int mt = 0; mt < 4; ++mt)
#pragma unroll
        for (int r = 0; r < 4; ++r) { minv[mt][r] = INFINITY; mini[mt][r] = 0; }

    __syncthreads();   // one-time full drain: tile0 DMA + Lyn visible; vmcnt=0

    int cur = 0;
    for (int tt = 0; tt < NT; ++tt) {
        const _Float16* LH = cur ? LdsH1 : LdsH0;
        const _Float16* LL = cur ? LdsL1 : LdsL0;
        _Float16* dH = cur ? LdsH0 : LdsH1;
        _Float16* dL = cur ? LdsL0 : LdsL1;
        const size_t gsnext = (size_t)((cbase0 + (tt + 1) * TILE_C) >> 4) * 1024;
        const int c0 = tt * TILE_C;
        const bool stg = (tt + 1 < NT);   // wave-uniform

#pragma unroll
        for (int ct = 0; ct < 4; ++ct) {
            // --- (1) T4 counted wait: retire own oldest 2 DMAs = the stage
            //     of THIS phase's read region (issued 4 phases ago). Never 0
            //     while staging continues; decreasing ladder on last tile. ---
            if (stg) {
                asm volatile("s_waitcnt vmcnt(6)" ::: "memory");
            } else {
                if      (ct == 0) asm volatile("s_waitcnt vmcnt(6)" ::: "memory");
                else if (ct == 1) asm volatile("s_waitcnt vmcnt(4)" ::: "memory");
                else if (ct == 2) asm volatile("s_waitcnt vmcnt(2)" ::: "memory");
                else              asm volatile("s_waitcnt vmcnt(0)" ::: "memory");
            }
            __builtin_amdgcn_sched_barrier(0);
            __builtin_amdgcn_s_barrier();        // partner's stage landed too
            __builtin_amdgcn_sched_barrier(0);

            // --- (2) ds_read this phase's B fragments ---
            const int chunk0 = (wy * 4 + ct) * 128 + lane;
            const int ccol   = wy * 64 + ct * 16;
            const float yn   = Lyn[c0 + ccol + l15];
            half8 bh0 = *(const half8*)(LH + (size_t)chunk0 * 8);
            half8 bl0 = *(const half8*)(LL + (size_t)chunk0 * 8);
            half8 bh1 = *(const half8*)(LH + (size_t)(chunk0 + 64) * 8);
            half8 bl1 = *(const half8*)(LL + (size_t)(chunk0 + 64) * 8);

            // --- (3) issue NEXT tile's SAME-phase stage (2 DMAs, own slice) ---
            if (stg) {
                const int jw = wy * 512 + ct * 128 + wq * 64;
                gl2lds16(Wh + gsnext + (size_t)(jw + lane) * 8, dH + (size_t)jw * 8);
                gl2lds16(Wl + gsnext + (size_t)(jw + lane) * 8, dL + (size_t)jw * 8);
            }

            // --- (4) MFMA cluster (rule #18: pin after lgkm wait) ---
            asm volatile("s_waitcnt lgkmcnt(0)" ::: "memory");
            __builtin_amdgcn_sched_barrier(0);
            const f32x4 yn4 = {yn, yn, yn, yn};  // acc init = yn (D: col=lane&15)
            f32x4 acc[4];
            __builtin_amdgcn_s_setprio(1);
#pragma unroll
            for (int mt = 0; mt < 4; ++mt) {
                // 3-term x (-2) with yn-init: acc ends as dist directly
                f32x4 a = __builtin_amdgcn_mfma_f32_16x16x32_f16(al[mt][0], bh0, yn4, 0, 0, 0);
                a = __builtin_amdgcn_mfma_f32_16x16x32_f16(ah[mt][0], bl0, a, 0, 0, 0);
                a = __builtin_amdgcn_mfma_f32_16x16x32_f16(ah[mt][0], bh0, a, 0, 0, 0);
                a = __builtin_amdgcn_mfma_f32_16x16x32_f16(al[mt][1], bh1, a, 0, 0, 0);
                a = __builtin_amdgcn_mfma_f32_16x16x32_f16(ah[mt][1], bl1, a, 0, 0, 0);
                a = __builtin_amdgcn_mfma_f32_16x16x32_f16(ah[mt][1], bh1, a, 0, 0, 0);
                acc[mt] = a;
            }
            __builtin_amdgcn_s_setprio(0);

            // --- (5) epilogue: acc IS dist; running argmin (c asc, strict <) ---
            const int cidx = cbase0 + c0 + ccol + l15;
#pragma unroll
            for (int mt = 0; mt < 4; ++mt) {
#pragma unroll
                for (int r = 0; r < 4; ++r) {
                    float s = acc[mt][r];
                    if (s < minv[mt][r]) { minv[mt][r] = s; mini[mt][r] = cidx; }
                }
            }
        }
        cur ^= 1;
    }

    // --- cross-lane: reduce over the 16 col-lanes (xor on low 4 lane bits) ---
#pragma unroll
    for (int mt = 0; mt < 4; ++mt) {
#pragma unroll
        for (int r = 0; r < 4; ++r) {
            float v = minv[mt][r];
            int   i = mini[mt][r];
#pragma unroll
            for (int m = 1; m <= 8; m <<= 1) {
                float ov = __shfl_xor(v, m, 64);
                int   oi = __shfl_xor(i, m, 64);
                if (ov < v || (ov == v && oi < i)) { v = ov; i = oi; }
            }
            if (l15 == 0) {
                int qoff = wq * 64 + mt * 16 + lq * 4 + r;   // row within block
                RedV[wy][qoff] = v;
                RedI[wy][qoff] = i;
            }
        }
    }
    __syncthreads();

    // --- combine c-halves, then FENCE-FREE cross-split combine via atomics ---
    if (t < BQ) {
        float v0 = RedV[0][t]; int i0 = RedI[0][t];
        float v1 = RedV[1][t]; int i1 = RedI[1][t];
        if (v1 < v0 || (v1 == v0 && i1 < i0)) { v0 = v1; i0 = i1; }
        atomicMin(&packed[qblk + t], pack_di(v0, i0));   // device-scope, coherent
    }
    // ensure this block's atomicMins are globally performed before the ticket
    asm volatile("s_waitcnt vmcnt(0)" ::: "memory");
    __syncthreads();
    if (t == 0) fin = (atomicAdd(&cnt[bx], 1) == CSPLIT - 1);
    __syncthreads();
    if (fin && t < BQ) {
        // atomic read-back (atomicMin with identity) -> final packed value
        unsigned long long v = atomicMin(&packed[qblk + t], ~0ull);
        out[qblk + t] = (int)(unsigned int)(v & 0xFFFFFFFFu);
    }
}

// ---------------------------------------------------------------------------
extern "C" void kernel_launch(void* const* d_in, const int* in_sizes, int n_in,
                              void* d_out, int out_size, void* d_ws, size_t ws_size,
                              hipStream_t stream) {
    const float* X = (const float*)d_in[0];   // [16384, 64]
    const float* W = (const float*)d_in[1];   // [8192, 64]

    // ws layout: Wh(1MB) | Wl(1MB) | ynorm(32KB) | packed(128KB) | cnt(512B)
    _Float16* Wh    = (_Float16*)d_ws;
    _Float16* Wl    = Wh + (size_t)NTOK * EMB;
    float*    ynorm = (float*)(Wl + (size_t)NTOK * EMB);
    unsigned long long* packed = (unsigned long long*)(ynorm + NTOK);
    int*      cnt   = (int*)(packed + NQ);
    int*      out   = (int*)d_out;

    prep_kernel<<<(NTOK * 8) / TPB, TPB, 0, stream>>>(W, Wh, Wl, ynorm, packed, cnt);
    dim3 grid(NXBLK, CSPLIT);
    vq_mfma_kernel<<<grid, TPB, 0, stream>>>(X, Wh, Wl, ynorm, packed, cnt, out);
}